// Round 14
// baseline (1147.047 us; speedup 1.0000x reference)
//
#include <hip/hip_runtime.h>
#include <stdint.h>

#define NN 6000
#define EE 120000
#define DD 128
#define CC 384
#define HDIM 512
#define OUT_NODES (NN*DD)
#define OUT_TOTAL (NN*DD + EE*DD)
#define NODE_LO (NN*DD)       /* 768000 u16: lo plane offset for nodes_hl  */
#define EDGE_LO (EE*DD)       /* 15360000 u16: lo plane offset for E*DD hl */
#define MAXDEG 256

typedef unsigned short u16;
typedef __bf16 bf16x8 __attribute__((ext_vector_type(8)));
typedef float f32x4 __attribute__((ext_vector_type(4)));

union V8 { u16 s[8]; uint4 v; };

__device__ __forceinline__ float bf2f(u16 u){ union{unsigned i; float f;} x; x.i=(unsigned)u<<16; return x.f; }
__device__ __forceinline__ u16 f2bf(float f){ union{unsigned i; float f;} x; x.f=f; unsigned r=(x.i + 0x7fffu + ((x.i>>16)&1u))>>16; return (u16)r; }
__device__ __forceinline__ float gelu_f(float v){ return 0.5f*v*(1.f + erff(v*0.70710678118654752f)); }

// async 16B global->LDS: per-lane global src, LDS dest = wave-uniform base + lane*16
__device__ __forceinline__ void stage16(void* l, const void* g) {
#if __has_builtin(__builtin_amdgcn_global_load_lds)
  __builtin_amdgcn_global_load_lds(
      (__attribute__((address_space(1))) void*)g,
      (__attribute__((address_space(3))) void*)l, 16, 0, 0);
#else
  *(uint4*)l = *(const uint4*)g;
#endif
}

// ---- shared MFMA phase for one 32-wide K step.
// buf layout: [0..4095]=Ah  [4096..8191]=Al  [8192..12287]=Bh  [12288..16383]=Bl (u16 idx)
// slot (row m, q) holds global k-chunk q ^ s(m), s(m)=(m^(m>>2))&3
__device__ __forceinline__ void mfma_step(const u16* buf, int wm, int wn, int lane,
                                          f32x4 acc[4][4])
{
  const int ml = lane & 15;
  const int qx = ((lane >> 4) ^ ((ml ^ (ml >> 2)) & 3)) & 3;
  bf16x8 a_h[4], a_l[4], v_h[4], v_l[4];
#pragma unroll
  for (int mi = 0; mi < 4; ++mi) {
    int ro = (wm*64 + mi*16 + ml)*32 + qx*8;
    a_h[mi] = *(const bf16x8*)(buf + ro);
    a_l[mi] = *(const bf16x8*)(buf + 4096 + ro);
  }
#pragma unroll
  for (int ni = 0; ni < 4; ++ni) {
    int ro = (wn*64 + ni*16 + ml)*32 + qx*8;
    v_h[ni] = *(const bf16x8*)(buf + 8192 + ro);
    v_l[ni] = *(const bf16x8*)(buf + 12288 + ro);
  }
#pragma unroll
  for (int mi = 0; mi < 4; ++mi)
#pragma unroll
    for (int ni = 0; ni < 4; ++ni) {
      acc[mi][ni] = __builtin_amdgcn_mfma_f32_16x16x32_bf16(a_h[mi], v_l[ni], acc[mi][ni], 0, 0, 0);
      acc[mi][ni] = __builtin_amdgcn_mfma_f32_16x16x32_bf16(a_l[mi], v_h[ni], acc[mi][ni], 0, 0, 0);
      acc[mi][ni] = __builtin_amdgcn_mfma_f32_16x16x32_bf16(a_h[mi], v_h[ni], acc[mi][ni], 0, 0, 0);
    }
}

// ---- single-A-plane MFMA step (k_score: eattr-hi only). Same buf layout, Al slot unused.
__device__ __forceinline__ void mfma_step_h1(const u16* buf, int wm, int wn, int lane,
                                             f32x4 acc[4][4])
{
  const int ml = lane & 15;
  const int qx = ((lane >> 4) ^ ((ml ^ (ml >> 2)) & 3)) & 3;
  bf16x8 a_h[4], v_h[4], v_l[4];
#pragma unroll
  for (int mi = 0; mi < 4; ++mi) {
    int ro = (wm*64 + mi*16 + ml)*32 + qx*8;
    a_h[mi] = *(const bf16x8*)(buf + ro);
  }
#pragma unroll
  for (int ni = 0; ni < 4; ++ni) {
    int ro = (wn*64 + ni*16 + ml)*32 + qx*8;
    v_h[ni] = *(const bf16x8*)(buf + 8192 + ro);
    v_l[ni] = *(const bf16x8*)(buf + 12288 + ro);
  }
#pragma unroll
  for (int mi = 0; mi < 4; ++mi)
#pragma unroll
    for (int ni = 0; ni < 4; ++ni) {
      acc[mi][ni] = __builtin_amdgcn_mfma_f32_16x16x32_bf16(a_h[mi], v_l[ni], acc[mi][ni], 0, 0, 0);
      acc[mi][ni] = __builtin_amdgcn_mfma_f32_16x16x32_bf16(a_h[mi], v_h[ni], acc[mi][ni], 0, 0, 0);
    }
}

// X-tile LDS swizzle: bijective within a row, 16B-chunk aligned, breaks bank collisions
// for 16-consecutive-row fragment reads (<=2-way, free).
__device__ __forceinline__ int xswz(int row, int col) {
  return row*128 + (col ^ ((row&3)<<3) ^ (((row>>2)&3)<<4));
}

// MFMA step for chain phases B/C: A from swizzled X tile (X0=hi,X1=lo, [128][128]),
// B from BB (staged like main path: [0..4095]=Bh, [4096..8191]=Bl with qs swizzle)
__device__ __forceinline__ void mfma_stepX(const u16* X0, const u16* X1, const u16* BB,
                                           int t, int wm, int wn, int lane, f32x4 acc[4][4])
{
  const int ml = lane & 15, qq = lane >> 4;
  const int qx = (qq ^ ((ml ^ (ml >> 2)) & 3)) & 3;
  bf16x8 a_h[4], a_l[4], v_h[4], v_l[4];
#pragma unroll
  for (int mi = 0; mi < 4; ++mi) {
    int o = xswz(wm*64 + mi*16 + ml, t*32 + qq*8);
    a_h[mi] = *(const bf16x8*)(X0 + o);
    a_l[mi] = *(const bf16x8*)(X1 + o);
  }
#pragma unroll
  for (int ni = 0; ni < 4; ++ni) {
    int ro = (wn*64 + ni*16 + ml)*32 + qx*8;
    v_h[ni] = *(const bf16x8*)(BB + ro);
    v_l[ni] = *(const bf16x8*)(BB + 4096 + ro);
  }
#pragma unroll
  for (int mi = 0; mi < 4; ++mi)
#pragma unroll
    for (int ni = 0; ni < 4; ++ni) {
      acc[mi][ni] = __builtin_amdgcn_mfma_f32_16x16x32_bf16(a_h[mi], v_l[ni], acc[mi][ni], 0, 0, 0);
      acc[mi][ni] = __builtin_amdgcn_mfma_f32_16x16x32_bf16(a_l[mi], v_h[ni], acc[mi][ni], 0, 0, 0);
      acc[mi][ni] = __builtin_amdgcn_mfma_f32_16x16x32_bf16(a_h[mi], v_h[ni], acc[mi][ni], 0, 0, 0);
    }
}

// ---- cooperative coalesced bf16 Z-gather (csr edge order):
// ZT[128][128] fp32 (64KB LDS) = bf2f(Zh[src[e]][zs0..]) + bf2f(Zh[snk[e]][zn0..]),
// e = csr[m0+row]. store swizzle: col ^ ((row>>2&1)<<4) -> fragment reads 2-way (free).
__device__ __forceinline__ void coop_loadZ_b(
    float* ZT, const u16* __restrict__ Zh, int zld, int zs0, int zn0,
    const int* __restrict__ src, const int* __restrict__ snk,
    const int* __restrict__ csr, int m0, int M, int tid)
{
#pragma unroll
  for (int it = 0; it < 8; ++it) {
    int idx = it*256 + tid;
    int row = idx >> 4, c8 = idx & 15;
    int gm = m0 + row; if (gm > M-1) gm = M-1;
    int e = csr[gm];
    V8 a8, b8;
    a8.v = *(const uint4*)(Zh + (size_t)src[e]*zld + zs0 + c8*8);
    b8.v = *(const uint4*)(Zh + (size_t)snk[e]*zld + zn0 + c8*8);
    int base = (c8*8) ^ (((row>>2)&1)<<4);
    float* d = ZT + row*128 + base;
#pragma unroll
    for (int j = 0; j < 8; ++j) d[j] = bf2f(a8.s[j]) + bf2f(b8.s[j]);
  }
}

// scatter bias(+gelu)'d acc tile into swizzled hi/lo X LDS planes
__device__ __forceinline__ void scatter_X(f32x4 acc[4][4], const float* bias, int gelu_on,
                                          u16* X0, u16* X1, int tid)
{
  const int lane = tid & 63, cl = lane & 15, qr = (lane>>4)&3;
  const int wm = (tid>>6)&1, wn = (tid>>7)&1;
#pragma unroll
  for (int ni = 0; ni < 4; ++ni) {
    float bv = bias[wn*64 + ni*16 + cl];
#pragma unroll
    for (int mi = 0; mi < 4; ++mi)
#pragma unroll
      for (int rg = 0; rg < 4; ++rg) {
        int row = wm*64 + mi*16 + qr*4 + rg;
        int col = wn*64 + ni*16 + cl;
        float v = acc[mi][ni][rg] + bv;
        if (gelu_on) v = gelu_f(v);
        u16 h = f2bf(v);
        int o = xswz(row, col);
        X0[o] = h; X1[o] = f2bf(v - bf2f(h));
      }
  }
}

// ---- fp32 scalar-store epilogue (bias optional) for small outputs (upd_f, dense_f)
__device__ __forceinline__ void epilogue_f32(
    f32x4 acc[4][4], const float* bias, float* Cp, int M, int ldc,
    int m0, int n0, int tid)
{
  const int lane = tid & 63;
  const int wm = (tid>>6)&1, wn = (tid>>7)&1;
  const int rl = wm*64 + ((lane>>4)&3)*4;
  const int cl0 = wn*64 + (lane & 15);
#pragma unroll
  for (int ni = 0; ni < 4; ++ni) {
    int gn = n0 + cl0 + ni*16;
    float bv = bias ? bias[gn] : 0.f;
#pragma unroll
    for (int mi = 0; mi < 4; ++mi)
#pragma unroll
      for (int rg = 0; rg < 4; ++rg) {
        int gm = m0 + rl + mi*16 + rg;
        if (gm < M) Cp[(size_t)gm*ldc + gn] = acc[mi][ni][rg] + bv;
      }
  }
}

// ---- single-plane bf16 epilogue (no bias): LDS-transpose, coalesced dwordx4 stores.
__device__ __forceinline__ void epilogue_h1(
    f32x4 acc[4][4], u16* Cp, u16* SM, int M, int ldn, int m0, int n0, int tid)
{
  const int lane = tid & 63, cl = lane & 15, qr = (lane>>4)&3;
  const int wm = (tid>>6)&1, wn = (tid>>7)&1;
#pragma unroll
  for (int mi = 0; mi < 4; ++mi)
#pragma unroll
    for (int ni = 0; ni < 4; ++ni)
#pragma unroll
      for (int rg = 0; rg < 4; ++rg) {
        int row = wm*64 + mi*16 + qr*4 + rg;
        int col = wn*64 + ni*16 + cl;
        SM[row*128 + (col ^ (qr<<4))] = f2bf(acc[mi][ni][rg]);
      }
  __syncthreads();
#pragma unroll
  for (int it = 0; it < 8; ++it) {
    int idx = it*256 + tid;
    int row = idx >> 4, blk = idx & 15;
    uint4 val = *(const uint4*)(SM + row*128 + ((blk*8) ^ (((row>>2)&3)<<4)));
    int gm = m0 + row;
    if (gm < M) *(uint4*)(Cp + (size_t)gm*ldn + n0 + blk*8) = val;
  }
  __syncthreads();
}

// ---- hi/lo bf16-split epilogue: bias(+gelu), LDS-transpose (swizzled, conflict-free),
//      coalesced dwordx4 stores (full 128B lines).
__device__ __forceinline__ void epilogue_hl(
    f32x4 acc[4][4], const float* bias, u16* Ch, u16* Cl, u16* SM,
    int M, int ldn, int gelu_on, int m0, int n0, int tid)
{
  const int lane = tid & 63, cl = lane & 15, qr = (lane>>4)&3;
  const int wm = (tid>>6)&1, wn = (tid>>7)&1;
#pragma unroll
  for (int ni = 0; ni < 4; ++ni) {
    float bv = bias[n0 + wn*64 + cl + ni*16];
#pragma unroll
    for (int mi = 0; mi < 4; ++mi)
#pragma unroll
      for (int rg = 0; rg < 4; ++rg) {
        float v = acc[mi][ni][rg] + bv;
        if (gelu_on) v = gelu_f(v);
        acc[mi][ni][rg] = v;
      }
  }
#pragma unroll
  for (int pass = 0; pass < 2; ++pass) {
    // scatter fragments into LDS tile; col swizzled by (row>>2)&3 == qr
#pragma unroll
    for (int mi = 0; mi < 4; ++mi)
#pragma unroll
      for (int ni = 0; ni < 4; ++ni)
#pragma unroll
        for (int rg = 0; rg < 4; ++rg) {
          int row = wm*64 + mi*16 + qr*4 + rg;
          int col = wn*64 + ni*16 + cl;
          float v = acc[mi][ni][rg];
          u16 h = f2bf(v);
          u16 w = pass ? f2bf(v - bf2f(h)) : h;
          SM[row*128 + (col ^ (qr<<4))] = w;
        }
    __syncthreads();
    u16* Cp = pass ? Cl : Ch;
#pragma unroll
    for (int it = 0; it < 8; ++it) {
      int idx = it*256 + tid;
      int row = idx >> 4, blk = idx & 15;
      uint4 val = *(const uint4*)(SM + row*128 + ((blk*8) ^ (((row>>2)&3)<<4)));
      int gm = m0 + row;
      if (gm < M) *(uint4*)(Cp + (size_t)gm*ldn + n0 + blk*8) = val;
    }
    __syncthreads();
  }
}

// ---------- GEMM, linear split A (hi/lo bf16) x split B; 2-phase double-buffered ----------
// epi: 3 = bias->fp32 (Cf) ; 5 = bias+gelu->hl (Ch/Cl) ; 6 = bias->hl ; 8 = no-bias->bf16 (Ch)
__global__ __launch_bounds__(256) void k_gemm2(
    const u16* A_h, const u16* A_l, int K,
    const u16* __restrict__ Bh, const u16* __restrict__ Bl,
    const float* __restrict__ bias, float* Cf,
    u16* Ch, u16* Cl, int M, int ldc, int epi)
{
  __shared__ __align__(16) u16 SM[2][16384];
  const int tid = threadIdx.x, lane = tid & 63;
  const int m0 = blockIdx.x*128, n0 = blockIdx.y*128;
  const int wm = (tid>>6)&1, wn = (tid>>7)&1;
  const u16* gA[2]; const u16* gAl[2]; const u16* gB[2]; const u16* gBl[2];
#pragma unroll
  for (int r = 0; r < 2; ++r) {
    int c = r*256 + tid, m = c>>2, q = c&3;
    int qs = q ^ ((m ^ (m>>2)) & 3);
    int gl = m0 + m; if (gl > M-1) gl = M-1;
    gA[r]  = A_h + (size_t)gl*K + qs*8;
    gAl[r] = A_l + (size_t)gl*K + qs*8;
    gB[r]  = Bh + (size_t)(n0+m)*K + qs*8;
    gBl[r] = Bl + (size_t)(n0+m)*K + qs*8;
  }
  auto stage = [&](int t, u16* buf) {
    int kt = t*32;
#pragma unroll
    for (int r = 0; r < 2; ++r) {
      int c8 = (r*256 + tid)*8;
      stage16(buf + c8,         gA[r]  + kt);
      stage16(buf + 4096 + c8,  gAl[r] + kt);
      stage16(buf + 8192 + c8,  gB[r]  + kt);
      stage16(buf + 12288 + c8, gBl[r] + kt);
    }
  };
  f32x4 acc[4][4] = {};
  const int nk = K >> 5;
  stage(0, SM[0]);
  for (int t = 0; t < nk; ++t) {
    __syncthreads();                       // drains vmcnt(0): buf[t&1] ready; all waves past t-1 reads
    if (t + 1 < nk) stage(t + 1, SM[(t+1)&1]);   // overlaps with this step's ds_read+MFMA
    mfma_step(SM[t&1], wm, wn, lane, acc);
  }
  __syncthreads();                          // all waves done reading before SM[0] reuse in epilogue
  if (epi == 3)      epilogue_f32(acc, bias, Cf, M, ldc, m0, n0, tid);
  else if (epi == 8) epilogue_h1(acc, Ch, SM[0], M, ldc, m0, n0, tid);
  else               epilogue_hl(acc, bias, Ch, Cl, SM[0], M, ldc, epi == 5, m0, n0, tid);
}

// ---------- fused MLP chain on gathered edge rows (R8 body — measured fastest):
//   X1 = gelu(feat @ B1 + b1)   feat = [nodes[src]|nodes[snk]|eattr], K=CC  (LDS-resident)
//   X2 = gelu(X1 @ B2 + b2)     (LDS; B2/B3 staged via BB buffer)
//   X3 =       X2 @ B3 + b3    -> global hi/lo (Xh/Xl)
__global__ __launch_bounds__(256) void k_mlp_chain(
    const u16* __restrict__ nodes_h, const u16* __restrict__ eattr_h,
    const int* __restrict__ src, const int* __restrict__ snk,
    const u16* __restrict__ B1h, const u16* __restrict__ B1l, const float* __restrict__ b1,
    const u16* __restrict__ B2h, const u16* __restrict__ B2l, const float* __restrict__ b2,
    const u16* __restrict__ B3h, const u16* __restrict__ B3l, const float* __restrict__ b3,
    u16* __restrict__ Xh, u16* __restrict__ Xl, int M)
{
  __shared__ __align__(16) u16 SM[2][16384];   // phase-A staging dbuf; then X-tile hi/lo
  __shared__ __align__(16) u16 BB[8192];       // phase-B/C weight tile (hi|lo)
  const int tid = threadIdx.x, lane = tid & 63;
  const int m0 = blockIdx.x*128;
  const int wm = (tid>>6)&1, wn = (tid>>7)&1;
  const u16* pr0[2]; const u16* pr1[2]; const u16* pr2[2];
  const u16* gB[2]; const u16* gBl[2];
  int soff[2];
#pragma unroll
  for (int r = 0; r < 2; ++r) {
    int c = r*256 + tid, m = c>>2, q = c&3;
    int qs = q ^ ((m ^ (m>>2)) & 3);
    int gl = m0 + m; if (gl > M-1) gl = M-1;
    pr0[r] = nodes_h + (size_t)src[gl]*DD + qs*8;
    pr1[r] = nodes_h + (size_t)snk[gl]*DD + qs*8;
    pr2[r] = eattr_h + (size_t)gl*DD + qs*8;
    gB[r]  = B1h + (size_t)m*CC + qs*8;
    gBl[r] = B1l + (size_t)m*CC + qs*8;
    soff[r] = m*128 + qs*8;              // [128 rows][K=128] weight offset for phases B/C
  }
  auto stage_g = [&](int t, u16* buf) {
    int reg = t >> 2, kk = (t & 3) * 32;
    const int LO = (reg == 2) ? EDGE_LO : NODE_LO;
#pragma unroll
    for (int r = 0; r < 2; ++r) {
      int c8 = (r*256 + tid)*8;
      const u16* g = (reg == 0 ? pr0[r] : reg == 1 ? pr1[r] : pr2[r]) + kk;
      stage16(buf + c8,         g);
      stage16(buf + 4096 + c8,  g + LO);
      stage16(buf + 8192 + c8,  gB[r]  + t*32);
      stage16(buf + 12288 + c8, gBl[r] + t*32);
    }
  };
  auto stageB = [&](const u16* Bh_, const u16* Bl_, int t) {
#pragma unroll
    for (int r = 0; r < 2; ++r) {
      int c8 = (r*256 + tid)*8;
      stage16(BB + c8,        Bh_ + soff[r] + t*32);
      stage16(BB + 4096 + c8, Bl_ + soff[r] + t*32);
    }
  };
  f32x4 acc[4][4] = {};
  // ---- phase A: gathered W1, K=CC ----
  stage_g(0, SM[0]);
  for (int t = 0; t < 12; ++t) {
    __syncthreads();
    if (t < 11) stage_g(t + 1, SM[(t+1)&1]);
    mfma_step(SM[t&1], wm, wn, lane, acc);
  }
  __syncthreads();                                  // all reads of SM done
  scatter_X(acc, b1, 1, (u16*)SM[0], (u16*)SM[1], tid);   // X1 -> LDS (gelu)
  __syncthreads();
  // ---- phase B: X1 @ W2, K=128 ----
#pragma unroll
  for (int mi = 0; mi < 4; ++mi)
#pragma unroll
    for (int ni = 0; ni < 4; ++ni)
#pragma unroll
      for (int rg = 0; rg < 4; ++rg) acc[mi][ni][rg] = 0.f;
  for (int t = 0; t < 4; ++t) {
    stageB(B2h, B2l, t);
    __syncthreads();                                // BB ready (vmcnt drain); prev BB reads done
    mfma_stepX((const u16*)SM[0], (const u16*)SM[1], BB, t, wm, wn, lane, acc);
    __syncthreads();
  }
  scatter_X(acc, b2, 1, (u16*)SM[0], (u16*)SM[1], tid);   // X2 -> LDS (gelu), overwrites X1
  __syncthreads();
  // ---- phase C: X2 @ W3, K=128 ----
#pragma unroll
  for (int mi = 0; mi < 4; ++mi)
#pragma unroll
    for (int ni = 0; ni < 4; ++ni)
#pragma unroll
      for (int rg = 0; rg < 4; ++rg) acc[mi][ni][rg] = 0.f;
  for (int t = 0; t < 4; ++t) {
    stageB(B3h, B3l, t);
    __syncthreads();
    mfma_stepX((const u16*)SM[0], (const u16*)SM[1], BB, t, wm, wn, lane, acc);
    __syncthreads();
  }
  epilogue_hl(acc, b3, Xh, Xl, (u16*)SM[0], M, 128, 0, m0, 0, tid);
}

// ---------- attention-score kernel: K=128 edge GEMM (csr edge order, eattr-HI only)
//            + bf16 Z gather + aA reduce ----
// flat grid 3752 = 8 XCDs x 469; all 4 head-blocks of an m-tile consecutive on ONE XCD.
// csr order => consecutive edges share snk node -> snk-half Z gather is L2-local.
// eattr lo-plane dropped: contributes <=0.2% rel to scores (same class as bf16 Zatt).
__global__ __launch_bounds__(256) void k_score(
    const u16* __restrict__ eattr_h,
    const int* __restrict__ src, const int* __restrict__ snk,
    const int* __restrict__ csr,
    const u16* __restrict__ Bh, const u16* __restrict__ Bl,     // aW_edge [512][128]
    const float* __restrict__ bias,                             // aW_b [512]
    const float* __restrict__ aAw, const float* __restrict__ aAb,
    const u16* __restrict__ Zatt,                               // bf16 [NN][1024]: 0..511 src, 512..1023 snk
    float* __restrict__ scores_out, int M)
{
  __shared__ __align__(16) u16 SM[2][16384];
  const int tid = threadIdx.x, lane = tid & 63;
  int p = (blockIdx.x & 7) * 469 + (blockIdx.x >> 3);
  const int bm = p >> 2, bn = p & 3;
  const int m0 = bm*128, n0 = bn*128;
  const int wm = (tid>>6)&1, wn = (tid>>7)&1;
  const u16* pr2[2]; const u16* gB[2]; const u16* gBl[2];
#pragma unroll
  for (int r = 0; r < 2; ++r) {
    int c = r*256 + tid, m = c>>2, q = c&3;
    int qs = q ^ ((m ^ (m>>2)) & 3);
    int gl = m0 + m; if (gl > M-1) gl = M-1;
    int ce = csr[gl];
    pr2[r] = eattr_h + (size_t)ce*DD + qs*8;
    gB[r]  = Bh + (size_t)(n0+m)*DD + qs*8;
    gBl[r] = Bl + (size_t)(n0+m)*DD + qs*8;
  }
  auto stage_s = [&](int t, u16* buf) {
#pragma unroll
    for (int r = 0; r < 2; ++r) {
      int c8 = (r*256 + tid)*8;
      stage16(buf + c8,         pr2[r] + t*32);     // eattr hi only
      stage16(buf + 8192 + c8,  gB[r]  + t*32);
      stage16(buf + 12288 + c8, gBl[r] + t*32);
    }
  };
  f32x4 acc[4][4] = {};
  stage_s(0, SM[0]);
  for (int t = 0; t < 4; ++t) {
    __syncthreads();
    if (t < 3) stage_s(t + 1, SM[(t+1)&1]);
    mfma_step_h1(SM[t&1], wm, wn, lane, acc);
  }
  __syncthreads();
  // ---- bf16 Z gather (csr order): ZT = Z[src[e]][n0..] + Z[snk[e]][512+n0..] ----
  float* ZT = (float*)SM;
  coop_loadZ_b(ZT, Zatt, 1024, n0, 512 + n0, src, snk, csr, m0, M, tid);
  __syncthreads();
  // pre-reduce into registers (reads ZT), then reuse SM[0] for cross-wave sred
  const int cl = lane & 15, qr = (lane>>4)&3;
  float pv[16];
#pragma unroll
  for (int mi = 0; mi < 4; ++mi)
#pragma unroll
    for (int rg = 0; rg < 4; ++rg) {
      int row = wm*64 + mi*16 + qr*4 + rg;
      int s = ((row>>2)&1)<<4;
      float pacc = 0.f;
#pragma unroll
      for (int ni = 0; ni < 4; ++ni) {
        int lc = wn*64 + ni*16 + cl;
        int gn = n0 + lc;
        float v = acc[mi][ni][rg] + bias[gn] + ZT[row*128 + (lc ^ s)];
        v = (v > 0.f) ? v : 0.2f*v;
        pacc += v * aAw[gn];
      }
      pacc += __shfl_xor(pacc, 1, 64); pacc += __shfl_xor(pacc, 2, 64);
      pacc += __shfl_xor(pacc, 4, 64); pacc += __shfl_xor(pacc, 8, 64);
      pv[mi*4 + rg] = pacc;
    }
  __syncthreads();                                  // ZT reads done before sred overwrites
  float* sred = (float*)SM[0];
#pragma unroll
  for (int mi = 0; mi < 4; ++mi)
#pragma unroll
    for (int rg = 0; rg < 4; ++rg)
      if (cl == 0) sred[wn*128 + wm*64 + mi*16 + qr*4 + rg] = pv[mi*4 + rg];
  __syncthreads();
  if (tid < 128) {
    int gm = m0 + tid;
    if (gm < M) scores_out[(size_t)csr[gm]*4 + bn] = sred[tid] + sred[128 + tid] + aAb[bn];
  }
}

// ---------------- small kernels ----------------
__global__ void k_detect(const u16* __restrict__ d, int n, int* __restrict__ flag) {
  __shared__ int cnt;
  if (threadIdx.x == 0) cnt = 0;
  __syncthreads();
  int c = 0;
  for (int i = threadIdx.x; i < n; i += blockDim.x) {
    int e = (d[i] >> 7) & 0xff;
    if (e >= 0xC0) ++c;
  }
  atomicAdd(&cnt, c);
  __syncthreads();
  if (threadIdx.x == 0) *flag = (cnt > 16) ? 1 : 0;
}

struct ConvDesc { const void* src; float* dst; int n; };
struct ConvArgs { ConvDesc d[30]; };
__global__ void k_conv32(ConvArgs a, const int* __restrict__ flag) {
  ConvDesc de = a.d[blockIdx.y];
  int fp = *flag;
  for (int i = blockIdx.x*256 + threadIdx.x; i < de.n; i += gridDim.x*256)
    de.dst[i] = fp ? ((const float*)de.src)[i] : bf2f(((const u16*)de.src)[i]);
}

struct PackDesc { const float* src; u16* dh; u16* dl; int K, N, sk, sh; };
struct PackArgs { PackDesc d[32]; int n; };
__global__ void k_pack2(PackArgs a) {
  PackDesc de = a.d[blockIdx.y];
  int total = de.K * de.N;
  for (int i = blockIdx.x*256 + threadIdx.x; i < total; i += gridDim.x*256) {
    int k = i / de.N, n = i - k*de.N;
    float x = de.src[(size_t)k*de.sk + (n & 127) + (n >> 7)*de.sh];
    u16 h = f2bf(x);
    de.dh[(size_t)n*de.K + k] = h;
    de.dl[(size_t)n*de.K + k] = f2bf(x - bf2f(h));
  }
}

__global__ void k_init_nodes(const int* __restrict__ seq, const float* __restrict__ emb,
                             float* __restrict__ nodes_f, u16* __restrict__ nh) {
  int i = blockIdx.x*256 + threadIdx.x;
  if (i >= NN*DD) return;
  int n = i >> 7, d = i & 127;
  float v = emb[seq[n]*DD + d];
  nodes_f[i] = v;
  u16 h = f2bf(v); nh[i] = h; nh[NODE_LO + i] = f2bf(v - bf2f(h));
}

__global__ void k_rbf_s(const float* __restrict__ dist, const float* __restrict__ W,
                        const float* __restrict__ b, u16* __restrict__ eh) {
  int e = blockIdx.x, t = threadIdx.x;   // 128 threads/edge
  float d = dist[e];
  float acc = b[t];
#pragma unroll
  for (int k = 0; k < 16; ++k) {
    float mu = 2.f + (20.f/15.f)*(float)k;
    float z = (d - mu)*0.8f;
    float r = expf(-z*z) + 1e-8f;
    acc += r*W[k*DD + t];
  }
  size_t idx = (size_t)e*DD + t;
  u16 h = f2bf(acc); eh[idx] = h; eh[(size_t)EDGE_LO + idx] = f2bf(acc - bf2f(h));
}

__global__ void k_hist(const int* __restrict__ snk, int* __restrict__ deg) {
  int e = blockIdx.x*256 + threadIdx.x;
  if (e < EE) atomicAdd(&deg[snk[e]], 1);
}
__global__ void k_scan(const int* __restrict__ deg, int* __restrict__ ptr, int* __restrict__ cursor, int n) {
  __shared__ int buf[1024];
  __shared__ int carry_s;
  int tid = threadIdx.x;
  if (tid == 0) carry_s = 0;
  __syncthreads();
  for (int base = 0; base < n; base += 1024) {
    int i = base + tid;
    int v = (i < n) ? deg[i] : 0;
    buf[tid] = v;
    __syncthreads();
    for (int off = 1; off < 1024; off <<= 1) {
      int t = (tid >= off) ? buf[tid - off] : 0;
      __syncthreads();
      buf[tid] += t;
      __syncthreads();
    }
    int excl = buf[tid] - v;
    int carry = carry_s;
    if (i < n) { ptr[i] = carry + excl; cursor[i] = carry + excl; }
    __syncthreads();
    if (tid == 1023) carry_s = carry + buf[1023];
    __syncthreads();
  }
  if (tid == 0) ptr[n] = carry_s;
}
__global__ void k_scatter(const int* __restrict__ snk, int* __restrict__ cursor, int* __restrict__ csr) {
  int e = blockIdx.x*256 + threadIdx.x;
  if (e < EE) { int p = atomicAdd(&cursor[snk[e]], 1); csr[p] = e; }
}

// ---- fused scatter-softmax + aggregation: one block per node, 128 threads.
// Exact same math/order as the previous k_softmax + k_aggregate pair.
__global__ void k_softmax_agg(const float* __restrict__ scores,
                              const int* __restrict__ ptr, const int* __restrict__ csr,
                              const u16* __restrict__ Xh, const u16* __restrict__ Xl,
                              u16* __restrict__ agg_h, u16* __restrict__ agg_l) {
  __shared__ float att_s[MAXDEG*4];
  __shared__ int   ce_s[MAXDEG];
  const int node = blockIdx.x, tid = threadIdx.x;
  const int b = ptr[node], e = ptr[node+1];
  int deg = e - b; if (deg > MAXDEG) deg = MAXDEG;   // Poisson(20): P(deg>256) ~ 0
  for (int i = tid; i < deg; i += 128) ce_s[i] = csr[b + i];
  __syncthreads();
  if (tid < 64) {
    int h = tid >> 4, j = tid & 15;
    float mx = -1e30f;
    for (int i = j; i < deg; i += 16) mx = fmaxf(mx, scores[(size_t)ce_s[i]*4 + h]);
    mx = fmaxf(mx, __shfl_xor(mx, 1, 64)); mx = fmaxf(mx, __shfl_xor(mx, 2, 64));
    mx = fmaxf(mx, __shfl_xor(mx, 4, 64)); mx = fmaxf(mx, __shfl_xor(mx, 8, 64));
    float s = 0.f;
    for (int i = j; i < deg; i += 16) s += expf(scores[(size_t)ce_s[i]*4 + h] - mx);
    s += __shfl_xor(s, 1, 64); s += __shfl_xor(s, 2, 64);
    s += __shfl_xor(s, 4, 64); s += __shfl_xor(s, 8, 64);
    float norm = s + (float)(e - b)*1e-12f;
    float inv = (e > b) ? 1.f/norm : 0.f;
    for (int i = j; i < deg; i += 16)
      att_s[i*4 + h] = expf(scores[(size_t)ce_s[i]*4 + h] - mx)*inv;
  }
  __syncthreads();
  const int d = tid;
  float a0=0.f, a1=0.f, a2=0.f, a3=0.f;
  for (int i = 0; i < deg; ++i) {
    int ed = ce_s[i];
    float4 a = *(const float4*)(att_s + i*4);
    size_t xo = (size_t)ed*DD + d;
    float v = bf2f(Xh[xo]) + bf2f(Xl[xo]);
    a0 += a.x*v; a1 += a.y*v; a2 += a.z*v; a3 += a.w*v;
  }
  size_t o = (size_t)node*HDIM + d;
  float vv[4] = {a0, a1, a2, a3};
#pragma unroll
  for (int h = 0; h < 4; ++h) {
    u16 hi = f2bf(vv[h]);
    agg_h[o + h*128] = hi;
    agg_l[o + h*128] = f2bf(vv[h] - bf2f(hi));
  }
}

// mode 0: x = nodes_f + upd ; mode 1: x = dense_f + upd. Writes nodes_f + hi/lo planes.
__global__ void k_ln_node(float* __restrict__ nodes_f,
                          const float* __restrict__ upd, const float* __restrict__ dense_f,
                          const float* __restrict__ g, const float* __restrict__ b,
                          int mode, int rows, u16* __restrict__ nh) {
  int r = blockIdx.x*4 + (threadIdx.x >> 6);
  if (r >= rows) return;
  int lane = threadIdx.x & 63;
  size_t o = (size_t)r*DD;
  float x0, x1;
  if (mode == 0) { x0 = nodes_f[o+lane]; x1 = nodes_f[o+lane+64]; }
  else           { x0 = dense_f[o+lane]; x1 = dense_f[o+lane+64]; }
  x0 += upd[o+lane]; x1 += upd[o+lane+64];
  float s = x0 + x1;
#pragma unroll
  for (int m = 1; m < 64; m <<= 1) s += __shfl_xor(s, m, 64);
  float mean = s * (1.f/128.f);
  float d0 = x0 - mean, d1 = x1 - mean;
  float vv = d0*d0 + d1*d1;
#pragma unroll
  for (int m = 1; m < 64; m <<= 1) vv += __shfl_xor(vv, m, 64);
  float inv = rsqrtf(vv*(1.f/128.f) + 1e-5f);
  float v0 = d0*inv*g[lane]    + b[lane];
  float v1 = d1*inv*g[lane+64] + b[lane+64];
  nodes_f[o+lane]    = v0;
  nodes_f[o+lane+64] = v1;
  u16 h0 = f2bf(v0), h1 = f2bf(v1);
  nh[o+lane] = h0;    nh[NODE_LO + o+lane]    = f2bf(v0 - bf2f(h0));
  nh[o+lane+64] = h1; nh[NODE_LO + o+lane+64] = f2bf(v1 - bf2f(h1));
}

// residual read from eh hi/lo planes; writes back eh hi/lo (no fp32 edge arena)
__global__ void k_ln_edge(const u16* __restrict__ Xh, const u16* __restrict__ Xl,
                          const float* __restrict__ g, const float* __restrict__ b,
                          int rows, u16* __restrict__ eh) {
  int r = blockIdx.x*4 + (threadIdx.x >> 6);
  if (r >= rows) return;
  int lane = threadIdx.x & 63;
  size_t o = (size_t)r*DD;
  float x0 = bf2f(eh[o+lane])    + bf2f(eh[(size_t)EDGE_LO + o+lane])
           + bf2f(Xh[o+lane])    + bf2f(Xl[o+lane]);
  float x1 = bf2f(eh[o+lane+64]) + bf2f(eh[(size_t)EDGE_LO + o+lane+64])
           + bf2f(Xh[o+lane+64]) + bf2f(Xl[o+lane+64]);
  float s = x0 + x1;
#pragma unroll
  for (int m = 1; m < 64; m <<= 1) s += __shfl_xor(s, m, 64);
  float mean = s * (1.f/128.f);
  float d0 = x0 - mean, d1 = x1 - mean;
  float vv = d0*d0 + d1*d1;
#pragma unroll
  for (int m = 1; m < 64; m <<= 1) vv += __shfl_xor(vv, m, 64);
  float inv = rsqrtf(vv*(1.f/128.f) + 1e-5f);
  float v0 = d0*inv*g[lane]    + b[lane];
  float v1 = d1*inv*g[lane+64] + b[lane+64];
  u16 h0 = f2bf(v0), h1 = f2bf(v1);
  eh[o+lane] = h0;    eh[(size_t)EDGE_LO + o+lane]    = f2bf(v0 - bf2f(h0));
  eh[o+lane+64] = h1; eh[(size_t)EDGE_LO + o+lane+64] = f2bf(v1 - bf2f(h1));
}

__global__ void k_finalize(const float* __restrict__ nodes_f, const u16* __restrict__ eh,
                           void* __restrict__ out, const int* __restrict__ flag) {
  int i = blockIdx.x*256 + threadIdx.x;
  if (i >= OUT_TOTAL) return;
  int fp = *flag;
  float v;
  if (i < OUT_NODES) v = nodes_f[i];
  else { int j = i - OUT_NODES; v = bf2f(eh[j]) + bf2f(eh[(size_t)EDGE_LO + j]); }
  if (fp) ((float*)out)[i] = v; else ((u16*)out)[i] = f2bf(v);
}

extern "C" void kernel_launch(void* const* d_in, const int* in_sizes, int n_in,
                              void* d_out, int out_size, void* d_ws, size_t ws_size,
                              hipStream_t stream)
{
  const int* seq_idx = (const int*)d_in[0];
  const int* esrc = (const int*)d_in[1];
  const int* esnk = ((const int*)d_in[1]) + EE;

  char* wsp = (char*)d_ws;
  size_t off = 0;
  auto carve = [&](size_t bytes)->char* {
    char* p = wsp + off; off += (bytes + 255) & ~(size_t)255; return p;
  };
  // Total ~187 MB (layout matches R10 exactly; pad replaces old att buffer)
  int* flag       = (int*)carve(256);
  float* nodes_f  = (float*)carve((size_t)NN*DD*4);
  float* upd_f    = (float*)carve((size_t)NN*DD*4);
  float* scores   = (float*)carve((size_t)EE*4*4);
  float* pad_att  = (float*)carve((size_t)EE*4*4);   // dead: keeps R10 buffer addresses
  float* dense_f  = (float*)carve((size_t)NN*DD*4);
  u16* Zatt       = (u16*)carve((size_t)NN*1024*2);     // bf16 node projections for scores
  u16* wpk_h      = (u16*)carve(557056ULL*2*2);
  u16* wpk_l      = (u16*)carve(557056ULL*2*2);
  int* deg        = (int*)carve((size_t)NN*4);
  int* ptrb       = (int*)carve((size_t)(NN+1)*4);
  int* cursor     = (int*)carve((size_t)NN*4);
  int* csr        = (int*)carve((size_t)EE*4);
  u16* nodes_h    = (u16*)carve((size_t)2*NN*DD*2);     // [hi | lo]
  u16* eattr_h    = (u16*)carve((size_t)2*EE*DD*2);     // [hi | lo]
  u16* X_h        = (u16*)carve((size_t)2*EE*DD*2);     // activation ping (hi|lo)
  u16* agg_h      = (u16*)carve((size_t)2*NN*HDIM*2);
  u16* dh_h       = (u16*)carve((size_t)2*NN*HDIM*2);
  u16* X_l   = X_h   + (size_t)EE*DD;
  u16* agg_l = agg_h + (size_t)NN*HDIM;
  u16* dh_l  = dh_h  + (size_t)NN*HDIM;
  (void)pad_att;

  static const int FCNT[32] = {0,0,120000,2688,2048,128,393216,1024,1024,8,
    98304,256,32768,256,32768,256, 131072,1024,131072,256,
    98304,256,32768,256,32768,256, 131072,256, 256,256,256,256};
  float* cf[32];
  for (int i = 2; i < 32; ++i) cf[i] = (float*)carve((size_t)FCNT[i]*4);
  (void)ws_size; (void)in_sizes; (void)n_in; (void)out_size;

  // ---- detect float storage dtype, canonicalize to FP32 arena ----
  k_detect<<<1, 1024, 0, stream>>>((const u16*)d_in[2], 120000, flag);
  ConvArgs ca;
  for (int i = 2; i < 32; ++i) { ca.d[i-2].src = d_in[i]; ca.d[i-2].dst = cf[i]; ca.d[i-2].n = FCNT[i]; }
  hipLaunchKernelGGL(k_conv32, dim3(96, 30), dim3(256), 0, stream, ca, flag);

  // ---- pack weights to [N,K] split hi/lo bf16 ----
  const size_t PW_L = 557056;
  PackArgs pa; int nd = 0;
  for (int l = 0; l < 2; ++l) {
    size_t base = l*PW_L;
    auto add = [&](const float* s, size_t doff, int K, int N, int sk, int sh){
      pa.d[nd].src = s; pa.d[nd].dh = wpk_h + doff; pa.d[nd].dl = wpk_l + doff;
      pa.d[nd].K = K; pa.d[nd].N = N; pa.d[nd].sk = sk; pa.d[nd].sh = sh; ++nd; };
    const float* aW = cf[6] + l*196608;
    add(aW,          base + 0,      128, 512, 128, 49152);  // aW src-slice
    add(aW + 16384,  base + 65536,  128, 512, 128, 49152);  // aW snk-slice
    add(aW + 32768,  base + 131072, 128, 512, 128, 49152);  // aW edge-slice
    add(cf[10] + l*49152, base + 196608, 384, 128, 128, 0); // nmlp_W1 (full K=384)
    add(cf[12] + l*16384, base + 245760, 128, 128, 128, 0); // nmlp_W2
    add(cf[14] + l*16384, base + 262144, 128, 128, 128, 0); // nmlp_W3
    add(cf[26] + l*65536, base + 278528, 512, 128, 128, 0); // aggr_W
    add(cf[16] + l*65536, base + 344064, 128, 512, 512, 128); // dmlp_W1
    add(cf[18] + l*65536, base + 409600, 512, 128, 128, 0); // dmlp_W2
    add(cf[20] + l*49152, base + 475136, 384, 128, 128, 0); // emlp_W1 (full K=384)
    add(cf[22] + l*16384, base + 524288, 128, 128, 128, 0); // emlp_W2
    add(cf[24] + l*16384, base + 540672, 128, 128, 128, 0); // emlp_W3
  }
  pa.n = nd;
  hipLaunchKernelGGL(k_pack2, dim3(256, nd), dim3(256), 0, stream, pa);

  k_init_nodes<<<(NN*DD + 255)/256, 256, 0, stream>>>(seq_idx, cf[3], nodes_f, nodes_h);
  k_rbf_s<<<EE, 128, 0, stream>>>(cf[2], cf[4], cf[5], eattr_h);

  (void)hipMemsetAsync(deg, 0, (size_t)NN*4, stream);
  k_hist<<<(EE + 255)/256, 256, 0, stream>>>(esnk, deg);
  k_scan<<<1, 1024, 0, stream>>>(deg, ptrb, cursor, NN);
  k_scatter<<<(EE + 255)/256, 256, 0, stream>>>(esnk, cursor, csr);

  for (int l = 0; l < 2; ++l) {
    const u16* bh = wpk_h + l*PW_L; const u16* bl = wpk_l + l*PW_L;
    // node projections for scores: Zatt[n][1024] (bf16) = nodes @ [aW_src|aW_snk]
    k_gemm2<<<dim3(47, 8), 256, 0, stream>>>(nodes_h, nodes_h + NODE_LO, 128,
        bh + 0, bl + 0, nullptr, nullptr, Zatt, nullptr, NN, 1024, 8);
    // attention scores: K=128 edge GEMM (csr order, eattr-hi only) + bf16 Z gather + aA reduce
    k_score<<<dim3(3752), 256, 0, stream>>>(eattr_h, esrc, esnk, csr,
        bh + 131072, bl + 131072, cf[7] + l*512, cf[8] + l*512, cf[9] + l*4,
        Zatt, scores, EE);
    // node-update MLP chain (R8 body): W1(gelu)->W2(gelu)->W3 -> X
    k_mlp_chain<<<dim3(938), 256, 0, stream>>>(nodes_h, eattr_h, esrc, esnk,
        bh + 196608, bl + 196608, cf[11] + l*128,
        bh + 245760, bl + 245760, cf[13] + l*128,
        bh + 262144, bl + 262144, cf[15] + l*128,
        X_h, X_l, EE);
    // fused scatter-softmax + aggregation (reads nupd hi/lo from X)
    k_softmax_agg<<<NN, 128, 0, stream>>>(scores, ptrb, csr, X_h, X_l, agg_h, agg_l);
    // upd = agg @ aggr_W + b  (fp32 out)
    k_gemm2<<<dim3(47, 1), 256, 0, stream>>>(agg_h, agg_l, 512, bh + 278528, bl + 278528,
        cf[27] + l*128, upd_f, nullptr, nullptr, NN, 128, 3);
    k_ln_node<<<(NN + 3)/4, 256, 0, stream>>>(nodes_f, upd_f, (const float*)nullptr,
        cf[28] + l*128, cf[29] + l*128, 0, NN, nodes_h);
    // dense MLP
    k_gemm2<<<dim3(47, 4), 256, 0, stream>>>(nodes_h, nodes_h + NODE_LO, 128,
        bh + 344064, bl + 344064, cf[17] + l*512, nullptr, dh_h, dh_l, NN, 512, 5);
    k_gemm2<<<dim3(47, 1), 256, 0, stream>>>(dh_h, dh_l, 512, bh + 409600, bl + 409600,
        cf[19] + l*128, dense_f, nullptr, nullptr, NN, 128, 3);
    k_ln_node<<<(NN + 3)/4, 256, 0, stream>>>(nodes_f, upd_f, dense_f,
        cf[28] + l*128, cf[29] + l*128, 1, NN, nodes_h);
    // edge MLP chain (R8 body): W1(gelu)->W2(gelu)->W3 -> X, then separate LN
    k_mlp_chain<<<dim3(938), 256, 0, stream>>>(nodes_h, eattr_h, esrc, esnk,
        bh + 475136, bl + 475136, cf[21] + l*128,
        bh + 524288, bl + 524288, cf[23] + l*128,
        bh + 540672, bl + 540672, cf[25] + l*128,
        X_h, X_l, EE);
    k_ln_edge<<<(EE + 3)/4, 256, 0, stream>>>(X_h, X_l,
        cf[30] + l*128, cf[31] + l*128, EE, eattr_h);
  }
  k_finalize<<<(OUT_TOTAL + 255)/256, 256, 0, stream>>>(nodes_f, eattr_h, d_out, flag);
}

// Round 15
// 1112.824 us; speedup vs baseline: 1.0308x; 1.0308x over previous
//
#include <hip/hip_runtime.h>
#include <stdint.h>

#define NN 6000
#define EE 120000
#define DD 128
#define CC 384
#define HDIM 512
#define OUT_NODES (NN*DD)
#define OUT_TOTAL (NN*DD + EE*DD)
#define NODE_LO (NN*DD)       /* 768000 u16: lo plane offset for nodes_hl  */
#define EDGE_LO (EE*DD)       /* 15360000 u16: lo plane offset for E*DD hl */
#define MAXDEG 256

typedef unsigned short u16;
typedef __bf16 bf16x8 __attribute__((ext_vector_type(8)));
typedef float f32x4 __attribute__((ext_vector_type(4)));

union V8 { u16 s[8]; uint4 v; };

__device__ __forceinline__ float bf2f(u16 u){ union{unsigned i; float f;} x; x.i=(unsigned)u<<16; return x.f; }
__device__ __forceinline__ u16 f2bf(float f){ union{unsigned i; float f;} x; x.f=f; unsigned r=(x.i + 0x7fffu + ((x.i>>16)&1u))>>16; return (u16)r; }
__device__ __forceinline__ float gelu_f(float v){ return 0.5f*v*(1.f + erff(v*0.70710678118654752f)); }

// async 16B global->LDS: per-lane global src, LDS dest = wave-uniform base + lane*16
__device__ __forceinline__ void stage16(void* l, const void* g) {
#if __has_builtin(__builtin_amdgcn_global_load_lds)
  __builtin_amdgcn_global_load_lds(
      (__attribute__((address_space(1))) void*)g,
      (__attribute__((address_space(3))) void*)l, 16, 0, 0);
#else
  *(uint4*)l = *(const uint4*)g;
#endif
}

// ---- shared MFMA phase for one 32-wide K step.
// buf layout: [0..4095]=Ah  [4096..8191]=Al  [8192..12287]=Bh  [12288..16383]=Bl (u16 idx)
// slot (row m, q) holds global k-chunk q ^ s(m), s(m)=(m^(m>>2))&3
__device__ __forceinline__ void mfma_step(const u16* buf, int wm, int wn, int lane,
                                          f32x4 acc[4][4])
{
  const int ml = lane & 15;
  const int qx = ((lane >> 4) ^ ((ml ^ (ml >> 2)) & 3)) & 3;
  bf16x8 a_h[4], a_l[4], v_h[4], v_l[4];
#pragma unroll
  for (int mi = 0; mi < 4; ++mi) {
    int ro = (wm*64 + mi*16 + ml)*32 + qx*8;
    a_h[mi] = *(const bf16x8*)(buf + ro);
    a_l[mi] = *(const bf16x8*)(buf + 4096 + ro);
  }
#pragma unroll
  for (int ni = 0; ni < 4; ++ni) {
    int ro = (wn*64 + ni*16 + ml)*32 + qx*8;
    v_h[ni] = *(const bf16x8*)(buf + 8192 + ro);
    v_l[ni] = *(const bf16x8*)(buf + 12288 + ro);
  }
#pragma unroll
  for (int mi = 0; mi < 4; ++mi)
#pragma unroll
    for (int ni = 0; ni < 4; ++ni) {
      acc[mi][ni] = __builtin_amdgcn_mfma_f32_16x16x32_bf16(a_h[mi], v_l[ni], acc[mi][ni], 0, 0, 0);
      acc[mi][ni] = __builtin_amdgcn_mfma_f32_16x16x32_bf16(a_l[mi], v_h[ni], acc[mi][ni], 0, 0, 0);
      acc[mi][ni] = __builtin_amdgcn_mfma_f32_16x16x32_bf16(a_h[mi], v_h[ni], acc[mi][ni], 0, 0, 0);
    }
}

// ---- single-A-plane MFMA step (k_score: eattr-hi only). Same buf layout, Al slot unused.
__device__ __forceinline__ void mfma_step_h1(const u16* buf, int wm, int wn, int lane,
                                             f32x4 acc[4][4])
{
  const int ml = lane & 15;
  const int qx = ((lane >> 4) ^ ((ml ^ (ml >> 2)) & 3)) & 3;
  bf16x8 a_h[4], v_h[4], v_l[4];
#pragma unroll
  for (int mi = 0; mi < 4; ++mi) {
    int ro = (wm*64 + mi*16 + ml)*32 + qx*8;
    a_h[mi] = *(const bf16x8*)(buf + ro);
  }
#pragma unroll
  for (int ni = 0; ni < 4; ++ni) {
    int ro = (wn*64 + ni*16 + ml)*32 + qx*8;
    v_h[ni] = *(const bf16x8*)(buf + 8192 + ro);
    v_l[ni] = *(const bf16x8*)(buf + 12288 + ro);
  }
#pragma unroll
  for (int mi = 0; mi < 4; ++mi)
#pragma unroll
    for (int ni = 0; ni < 4; ++ni) {
      acc[mi][ni] = __builtin_amdgcn_mfma_f32_16x16x32_bf16(a_h[mi], v_l[ni], acc[mi][ni], 0, 0, 0);
      acc[mi][ni] = __builtin_amdgcn_mfma_f32_16x16x32_bf16(a_h[mi], v_h[ni], acc[mi][ni], 0, 0, 0);
    }
}

// X-tile LDS swizzle: bijective within a row, 16B-chunk aligned, breaks bank collisions
// for 16-consecutive-row fragment reads (<=2-way, free).
__device__ __forceinline__ int xswz(int row, int col) {
  return row*128 + (col ^ ((row&3)<<3) ^ (((row>>2)&3)<<4));
}

// MFMA step for chain phases B/C: A from swizzled X tile (X0=hi,X1=lo, [128][128]),
// B from BB (staged like main path: [0..4095]=Bh, [4096..8191]=Bl with qs swizzle)
__device__ __forceinline__ void mfma_stepX(const u16* X0, const u16* X1, const u16* BB,
                                           int t, int wm, int wn, int lane, f32x4 acc[4][4])
{
  const int ml = lane & 15, qq = lane >> 4;
  const int qx = (qq ^ ((ml ^ (ml >> 2)) & 3)) & 3;
  bf16x8 a_h[4], a_l[4], v_h[4], v_l[4];
#pragma unroll
  for (int mi = 0; mi < 4; ++mi) {
    int o = xswz(wm*64 + mi*16 + ml, t*32 + qq*8);
    a_h[mi] = *(const bf16x8*)(X0 + o);
    a_l[mi] = *(const bf16x8*)(X1 + o);
  }
#pragma unroll
  for (int ni = 0; ni < 4; ++ni) {
    int ro = (wn*64 + ni*16 + ml)*32 + qx*8;
    v_h[ni] = *(const bf16x8*)(BB + ro);
    v_l[ni] = *(const bf16x8*)(BB + 4096 + ro);
  }
#pragma unroll
  for (int mi = 0; mi < 4; ++mi)
#pragma unroll
    for (int ni = 0; ni < 4; ++ni) {
      acc[mi][ni] = __builtin_amdgcn_mfma_f32_16x16x32_bf16(a_h[mi], v_l[ni], acc[mi][ni], 0, 0, 0);
      acc[mi][ni] = __builtin_amdgcn_mfma_f32_16x16x32_bf16(a_l[mi], v_h[ni], acc[mi][ni], 0, 0, 0);
      acc[mi][ni] = __builtin_amdgcn_mfma_f32_16x16x32_bf16(a_h[mi], v_h[ni], acc[mi][ni], 0, 0, 0);
    }
}

// ---- cooperative coalesced bf16 Z-gather (csr edge order):
// ZT[128][128] fp32 (64KB LDS) = bf2f(Zh[src[e]][zs0..]) + bf2f(Zh[snk[e]][zn0..]),
// e = csr[m0+row]. store swizzle: col ^ ((row>>2&1)<<4) -> fragment reads 2-way (free).
__device__ __forceinline__ void coop_loadZ_b(
    float* ZT, const u16* __restrict__ Zh, int zld, int zs0, int zn0,
    const int* __restrict__ src, const int* __restrict__ snk,
    const int* __restrict__ csr, int m0, int M, int tid)
{
#pragma unroll
  for (int it = 0; it < 8; ++it) {
    int idx = it*256 + tid;
    int row = idx >> 4, c8 = idx & 15;
    int gm = m0 + row; if (gm > M-1) gm = M-1;
    int e = csr[gm];
    V8 a8, b8;
    a8.v = *(const uint4*)(Zh + (size_t)src[e]*zld + zs0 + c8*8);
    b8.v = *(const uint4*)(Zh + (size_t)snk[e]*zld + zn0 + c8*8);
    int base = (c8*8) ^ (((row>>2)&1)<<4);
    float* d = ZT + row*128 + base;
#pragma unroll
    for (int j = 0; j < 8; ++j) d[j] = bf2f(a8.s[j]) + bf2f(b8.s[j]);
  }
}

// scatter bias(+gelu)'d acc tile into swizzled hi/lo X LDS planes
__device__ __forceinline__ void scatter_X(f32x4 acc[4][4], const float* bias, int gelu_on,
                                          u16* X0, u16* X1, int tid)
{
  const int lane = tid & 63, cl = lane & 15, qr = (lane>>4)&3;
  const int wm = (tid>>6)&1, wn = (tid>>7)&1;
#pragma unroll
  for (int ni = 0; ni < 4; ++ni) {
    float bv = bias[wn*64 + ni*16 + cl];
#pragma unroll
    for (int mi = 0; mi < 4; ++mi)
#pragma unroll
      for (int rg = 0; rg < 4; ++rg) {
        int row = wm*64 + mi*16 + qr*4 + rg;
        int col = wn*64 + ni*16 + cl;
        float v = acc[mi][ni][rg] + bv;
        if (gelu_on) v = gelu_f(v);
        u16 h = f2bf(v);
        int o = xswz(row, col);
        X0[o] = h; X1[o] = f2bf(v - bf2f(h));
      }
  }
}

// ---- fp32 scalar-store epilogue (bias optional) for small outputs (upd_f, dense_f)
__device__ __forceinline__ void epilogue_f32(
    f32x4 acc[4][4], const float* bias, float* Cp, int M, int ldc,
    int m0, int n0, int tid)
{
  const int lane = tid & 63;
  const int wm = (tid>>6)&1, wn = (tid>>7)&1;
  const int rl = wm*64 + ((lane>>4)&3)*4;
  const int cl0 = wn*64 + (lane & 15);
#pragma unroll
  for (int ni = 0; ni < 4; ++ni) {
    int gn = n0 + cl0 + ni*16;
    float bv = bias ? bias[gn] : 0.f;
#pragma unroll
    for (int mi = 0; mi < 4; ++mi)
#pragma unroll
      for (int rg = 0; rg < 4; ++rg) {
        int gm = m0 + rl + mi*16 + rg;
        if (gm < M) Cp[(size_t)gm*ldc + gn] = acc[mi][ni][rg] + bv;
      }
  }
}

// ---- single-plane bf16 epilogue (no bias): LDS-transpose, coalesced dwordx4 stores.
__device__ __forceinline__ void epilogue_h1(
    f32x4 acc[4][4], u16* Cp, u16* SM, int M, int ldn, int m0, int n0, int tid)
{
  const int lane = tid & 63, cl = lane & 15, qr = (lane>>4)&3;
  const int wm = (tid>>6)&1, wn = (tid>>7)&1;
#pragma unroll
  for (int mi = 0; mi < 4; ++mi)
#pragma unroll
    for (int ni = 0; ni < 4; ++ni)
#pragma unroll
      for (int rg = 0; rg < 4; ++rg) {
        int row = wm*64 + mi*16 + qr*4 + rg;
        int col = wn*64 + ni*16 + cl;
        SM[row*128 + (col ^ (qr<<4))] = f2bf(acc[mi][ni][rg]);
      }
  __syncthreads();
#pragma unroll
  for (int it = 0; it < 8; ++it) {
    int idx = it*256 + tid;
    int row = idx >> 4, blk = idx & 15;
    uint4 val = *(const uint4*)(SM + row*128 + ((blk*8) ^ (((row>>2)&3)<<4)));
    int gm = m0 + row;
    if (gm < M) *(uint4*)(Cp + (size_t)gm*ldn + n0 + blk*8) = val;
  }
  __syncthreads();
}

// ---- single-plane bf16 epilogue WITH bias (no gelu): chain X3 output.
__device__ __forceinline__ void epilogue_h1b(
    f32x4 acc[4][4], const float* bias, u16* Cp, u16* SM,
    int M, int ldn, int m0, int n0, int tid)
{
  const int lane = tid & 63, cl = lane & 15, qr = (lane>>4)&3;
  const int wm = (tid>>6)&1, wn = (tid>>7)&1;
#pragma unroll
  for (int ni = 0; ni < 4; ++ni) {
    float bv = bias[n0 + wn*64 + ni*16 + cl];
#pragma unroll
    for (int mi = 0; mi < 4; ++mi)
#pragma unroll
      for (int rg = 0; rg < 4; ++rg) {
        int row = wm*64 + mi*16 + qr*4 + rg;
        int col = wn*64 + ni*16 + cl;
        SM[row*128 + (col ^ (qr<<4))] = f2bf(acc[mi][ni][rg] + bv);
      }
  }
  __syncthreads();
#pragma unroll
  for (int it = 0; it < 8; ++it) {
    int idx = it*256 + tid;
    int row = idx >> 4, blk = idx & 15;
    uint4 val = *(const uint4*)(SM + row*128 + ((blk*8) ^ (((row>>2)&3)<<4)));
    int gm = m0 + row;
    if (gm < M) *(uint4*)(Cp + (size_t)gm*ldn + n0 + blk*8) = val;
  }
  __syncthreads();
}

// ---- hi/lo bf16-split epilogue: bias(+gelu), LDS-transpose (swizzled, conflict-free),
//      coalesced dwordx4 stores (full 128B lines).
__device__ __forceinline__ void epilogue_hl(
    f32x4 acc[4][4], const float* bias, u16* Ch, u16* Cl, u16* SM,
    int M, int ldn, int gelu_on, int m0, int n0, int tid)
{
  const int lane = tid & 63, cl = lane & 15, qr = (lane>>4)&3;
  const int wm = (tid>>6)&1, wn = (tid>>7)&1;
#pragma unroll
  for (int ni = 0; ni < 4; ++ni) {
    float bv = bias[n0 + wn*64 + cl + ni*16];
#pragma unroll
    for (int mi = 0; mi < 4; ++mi)
#pragma unroll
      for (int rg = 0; rg < 4; ++rg) {
        float v = acc[mi][ni][rg] + bv;
        if (gelu_on) v = gelu_f(v);
        acc[mi][ni][rg] = v;
      }
  }
#pragma unroll
  for (int pass = 0; pass < 2; ++pass) {
    // scatter fragments into LDS tile; col swizzled by (row>>2)&3 == qr
#pragma unroll
    for (int mi = 0; mi < 4; ++mi)
#pragma unroll
      for (int ni = 0; ni < 4; ++ni)
#pragma unroll
        for (int rg = 0; rg < 4; ++rg) {
          int row = wm*64 + mi*16 + qr*4 + rg;
          int col = wn*64 + ni*16 + cl;
          float v = acc[mi][ni][rg];
          u16 h = f2bf(v);
          u16 w = pass ? f2bf(v - bf2f(h)) : h;
          SM[row*128 + (col ^ (qr<<4))] = w;
        }
    __syncthreads();
    u16* Cp = pass ? Cl : Ch;
#pragma unroll
    for (int it = 0; it < 8; ++it) {
      int idx = it*256 + tid;
      int row = idx >> 4, blk = idx & 15;
      uint4 val = *(const uint4*)(SM + row*128 + ((blk*8) ^ (((row>>2)&3)<<4)));
      int gm = m0 + row;
      if (gm < M) *(uint4*)(Cp + (size_t)gm*ldn + n0 + blk*8) = val;
    }
    __syncthreads();
  }
}

// ---------- GEMM, linear split A (hi/lo bf16) x split B; 2-phase double-buffered ----------
// epi: 3 = bias->fp32 (Cf) ; 5 = bias+gelu->hl (Ch/Cl) ; 6 = bias->hl ; 8 = no-bias->bf16 (Ch)
__global__ __launch_bounds__(256) void k_gemm2(
    const u16* A_h, const u16* A_l, int K,
    const u16* __restrict__ Bh, const u16* __restrict__ Bl,
    const float* __restrict__ bias, float* Cf,
    u16* Ch, u16* Cl, int M, int ldc, int epi)
{
  __shared__ __align__(16) u16 SM[2][16384];
  const int tid = threadIdx.x, lane = tid & 63;
  const int m0 = blockIdx.x*128, n0 = blockIdx.y*128;
  const int wm = (tid>>6)&1, wn = (tid>>7)&1;
  const u16* gA[2]; const u16* gAl[2]; const u16* gB[2]; const u16* gBl[2];
#pragma unroll
  for (int r = 0; r < 2; ++r) {
    int c = r*256 + tid, m = c>>2, q = c&3;
    int qs = q ^ ((m ^ (m>>2)) & 3);
    int gl = m0 + m; if (gl > M-1) gl = M-1;
    gA[r]  = A_h + (size_t)gl*K + qs*8;
    gAl[r] = A_l + (size_t)gl*K + qs*8;
    gB[r]  = Bh + (size_t)(n0+m)*K + qs*8;
    gBl[r] = Bl + (size_t)(n0+m)*K + qs*8;
  }
  auto stage = [&](int t, u16* buf) {
    int kt = t*32;
#pragma unroll
    for (int r = 0; r < 2; ++r) {
      int c8 = (r*256 + tid)*8;
      stage16(buf + c8,         gA[r]  + kt);
      stage16(buf + 4096 + c8,  gAl[r] + kt);
      stage16(buf + 8192 + c8,  gB[r]  + kt);
      stage16(buf + 12288 + c8, gBl[r] + kt);
    }
  };
  f32x4 acc[4][4] = {};
  const int nk = K >> 5;
  stage(0, SM[0]);
  for (int t = 0; t < nk; ++t) {
    __syncthreads();                       // drains vmcnt(0): buf[t&1] ready; all waves past t-1 reads
    if (t + 1 < nk) stage(t + 1, SM[(t+1)&1]);   // overlaps with this step's ds_read+MFMA
    mfma_step(SM[t&1], wm, wn, lane, acc);
  }
  __syncthreads();                          // all waves done reading before SM[0] reuse in epilogue
  if (epi == 3)      epilogue_f32(acc, bias, Cf, M, ldc, m0, n0, tid);
  else if (epi == 8) epilogue_h1(acc, Ch, SM[0], M, ldc, m0, n0, tid);
  else               epilogue_hl(acc, bias, Ch, Cl, SM[0], M, ldc, epi == 5, m0, n0, tid);
}

// ---------- fused MLP chain on gathered edge rows (R8 body — measured fastest):
//   X1 = gelu(feat @ B1 + b1)   feat = [nodes[src]|nodes[snk]|eattr], K=CC  (LDS-resident)
//   X2 = gelu(X1 @ B2 + b2)     (LDS; B2/B3 staged via BB buffer)
//   X3 =       X2 @ B3 + b3    -> global bf16 single plane (Xh)
__global__ __launch_bounds__(256) void k_mlp_chain(
    const u16* __restrict__ nodes_h, const u16* __restrict__ eattr_h,
    const int* __restrict__ src, const int* __restrict__ snk,
    const u16* __restrict__ B1h, const u16* __restrict__ B1l, const float* __restrict__ b1,
    const u16* __restrict__ B2h, const u16* __restrict__ B2l, const float* __restrict__ b2,
    const u16* __restrict__ B3h, const u16* __restrict__ B3l, const float* __restrict__ b3,
    u16* __restrict__ Xh, int M)
{
  __shared__ __align__(16) u16 SM[2][16384];   // phase-A staging dbuf; then X-tile hi/lo
  __shared__ __align__(16) u16 BB[8192];       // phase-B/C weight tile (hi|lo)
  const int tid = threadIdx.x, lane = tid & 63;
  const int m0 = blockIdx.x*128;
  const int wm = (tid>>6)&1, wn = (tid>>7)&1;
  const u16* pr0[2]; const u16* pr1[2]; const u16* pr2[2];
  const u16* gB[2]; const u16* gBl[2];
  int soff[2];
#pragma unroll
  for (int r = 0; r < 2; ++r) {
    int c = r*256 + tid, m = c>>2, q = c&3;
    int qs = q ^ ((m ^ (m>>2)) & 3);
    int gl = m0 + m; if (gl > M-1) gl = M-1;
    pr0[r] = nodes_h + (size_t)src[gl]*DD + qs*8;
    pr1[r] = nodes_h + (size_t)snk[gl]*DD + qs*8;
    pr2[r] = eattr_h + (size_t)gl*DD + qs*8;
    gB[r]  = B1h + (size_t)m*CC + qs*8;
    gBl[r] = B1l + (size_t)m*CC + qs*8;
    soff[r] = m*128 + qs*8;              // [128 rows][K=128] weight offset for phases B/C
  }
  auto stage_g = [&](int t, u16* buf) {
    int reg = t >> 2, kk = (t & 3) * 32;
    const int LO = (reg == 2) ? EDGE_LO : NODE_LO;
#pragma unroll
    for (int r = 0; r < 2; ++r) {
      int c8 = (r*256 + tid)*8;
      const u16* g = (reg == 0 ? pr0[r] : reg == 1 ? pr1[r] : pr2[r]) + kk;
      stage16(buf + c8,         g);
      stage16(buf + 4096 + c8,  g + LO);
      stage16(buf + 8192 + c8,  gB[r]  + t*32);
      stage16(buf + 12288 + c8, gBl[r] + t*32);
    }
  };
  auto stageB = [&](const u16* Bh_, const u16* Bl_, int t) {
#pragma unroll
    for (int r = 0; r < 2; ++r) {
      int c8 = (r*256 + tid)*8;
      stage16(BB + c8,        Bh_ + soff[r] + t*32);
      stage16(BB + 4096 + c8, Bl_ + soff[r] + t*32);
    }
  };
  f32x4 acc[4][4] = {};
  // ---- phase A: gathered W1, K=CC ----
  stage_g(0, SM[0]);
  for (int t = 0; t < 12; ++t) {
    __syncthreads();
    if (t < 11) stage_g(t + 1, SM[(t+1)&1]);
    mfma_step(SM[t&1], wm, wn, lane, acc);
  }
  __syncthreads();                                  // all reads of SM done
  scatter_X(acc, b1, 1, (u16*)SM[0], (u16*)SM[1], tid);   // X1 -> LDS (gelu)
  __syncthreads();
  // ---- phase B: X1 @ W2, K=128 ----
#pragma unroll
  for (int mi = 0; mi < 4; ++mi)
#pragma unroll
    for (int ni = 0; ni < 4; ++ni)
#pragma unroll
      for (int rg = 0; rg < 4; ++rg) acc[mi][ni][rg] = 0.f;
  for (int t = 0; t < 4; ++t) {
    stageB(B2h, B2l, t);
    __syncthreads();                                // BB ready (vmcnt drain); prev BB reads done
    mfma_stepX((const u16*)SM[0], (const u16*)SM[1], BB, t, wm, wn, lane, acc);
    __syncthreads();
  }
  scatter_X(acc, b2, 1, (u16*)SM[0], (u16*)SM[1], tid);   // X2 -> LDS (gelu), overwrites X1
  __syncthreads();
  // ---- phase C: X2 @ W3, K=128 ----
#pragma unroll
  for (int mi = 0; mi < 4; ++mi)
#pragma unroll
    for (int ni = 0; ni < 4; ++ni)
#pragma unroll
      for (int rg = 0; rg < 4; ++rg) acc[mi][ni][rg] = 0.f;
  for (int t = 0; t < 4; ++t) {
    stageB(B3h, B3l, t);
    __syncthreads();
    mfma_stepX((const u16*)SM[0], (const u16*)SM[1], BB, t, wm, wn, lane, acc);
    __syncthreads();
  }
  epilogue_h1b(acc, b3, Xh, (u16*)SM[0], M, 128, m0, 0, tid);
}

// ---------- attention-score kernel: K=128 edge GEMM (csr edge order, eattr-HI only)
//            + bf16 Z gather + aA reduce ----
// flat grid 3752 = 8 XCDs x 469; all 4 head-blocks of an m-tile consecutive on ONE XCD.
// csr order => consecutive edges share snk node -> snk-half Z gather is L2-local.
// eattr lo-plane dropped: contributes <=0.2% rel to scores (same class as bf16 Zatt).
__global__ __launch_bounds__(256) void k_score(
    const u16* __restrict__ eattr_h,
    const int* __restrict__ src, const int* __restrict__ snk,
    const int* __restrict__ csr,
    const u16* __restrict__ Bh, const u16* __restrict__ Bl,     // aW_edge [512][128]
    const float* __restrict__ bias,                             // aW_b [512]
    const float* __restrict__ aAw, const float* __restrict__ aAb,
    const u16* __restrict__ Zatt,                               // bf16 [NN][1024]: 0..511 src, 512..1023 snk
    float* __restrict__ scores_out, int M)
{
  __shared__ __align__(16) u16 SM[2][16384];
  const int tid = threadIdx.x, lane = tid & 63;
  int p = (blockIdx.x & 7) * 469 + (blockIdx.x >> 3);
  const int bm = p >> 2, bn = p & 3;
  const int m0 = bm*128, n0 = bn*128;
  const int wm = (tid>>6)&1, wn = (tid>>7)&1;
  const u16* pr2[2]; const u16* gB[2]; const u16* gBl[2];
#pragma unroll
  for (int r = 0; r < 2; ++r) {
    int c = r*256 + tid, m = c>>2, q = c&3;
    int qs = q ^ ((m ^ (m>>2)) & 3);
    int gl = m0 + m; if (gl > M-1) gl = M-1;
    int ce = csr[gl];
    pr2[r] = eattr_h + (size_t)ce*DD + qs*8;
    gB[r]  = Bh + (size_t)(n0+m)*DD + qs*8;
    gBl[r] = Bl + (size_t)(n0+m)*DD + qs*8;
  }
  auto stage_s = [&](int t, u16* buf) {
#pragma unroll
    for (int r = 0; r < 2; ++r) {
      int c8 = (r*256 + tid)*8;
      stage16(buf + c8,         pr2[r] + t*32);     // eattr hi only
      stage16(buf + 8192 + c8,  gB[r]  + t*32);
      stage16(buf + 12288 + c8, gBl[r] + t*32);
    }
  };
  f32x4 acc[4][4] = {};
  stage_s(0, SM[0]);
  for (int t = 0; t < 4; ++t) {
    __syncthreads();
    if (t < 3) stage_s(t + 1, SM[(t+1)&1]);
    mfma_step_h1(SM[t&1], wm, wn, lane, acc);
  }
  __syncthreads();
  // ---- bf16 Z gather (csr order): ZT = Z[src[e]][n0..] + Z[snk[e]][512+n0..] ----
  float* ZT = (float*)SM;
  coop_loadZ_b(ZT, Zatt, 1024, n0, 512 + n0, src, snk, csr, m0, M, tid);
  __syncthreads();
  // pre-reduce into registers (reads ZT), then reuse SM[0] for cross-wave sred
  const int cl = lane & 15, qr = (lane>>4)&3;
  float pv[16];
#pragma unroll
  for (int mi = 0; mi < 4; ++mi)
#pragma unroll
    for (int rg = 0; rg < 4; ++rg) {
      int row = wm*64 + mi*16 + qr*4 + rg;
      int s = ((row>>2)&1)<<4;
      float pacc = 0.f;
#pragma unroll
      for (int ni = 0; ni < 4; ++ni) {
        int lc = wn*64 + ni*16 + cl;
        int gn = n0 + lc;
        float v = acc[mi][ni][rg] + bias[gn] + ZT[row*128 + (lc ^ s)];
        v = (v > 0.f) ? v : 0.2f*v;
        pacc += v * aAw[gn];
      }
      pacc += __shfl_xor(pacc, 1, 64); pacc += __shfl_xor(pacc, 2, 64);
      pacc += __shfl_xor(pacc, 4, 64); pacc += __shfl_xor(pacc, 8, 64);
      pv[mi*4 + rg] = pacc;
    }
  __syncthreads();                                  // ZT reads done before sred overwrites
  float* sred = (float*)SM[0];
#pragma unroll
  for (int mi = 0; mi < 4; ++mi)
#pragma unroll
    for (int rg = 0; rg < 4; ++rg)
      if (cl == 0) sred[wn*128 + wm*64 + mi*16 + qr*4 + rg] = pv[mi*4 + rg];
  __syncthreads();
  if (tid < 128) {
    int gm = m0 + tid;
    if (gm < M) scores_out[(size_t)csr[gm]*4 + bn] = sred[tid] + sred[128 + tid] + aAb[bn];
  }
}

// ---------------- small kernels ----------------
__global__ void k_detect(const u16* __restrict__ d, int n, int* __restrict__ flag) {
  __shared__ int cnt;
  if (threadIdx.x == 0) cnt = 0;
  __syncthreads();
  int c = 0;
  for (int i = threadIdx.x; i < n; i += blockDim.x) {
    int e = (d[i] >> 7) & 0xff;
    if (e >= 0xC0) ++c;
  }
  atomicAdd(&cnt, c);
  __syncthreads();
  if (threadIdx.x == 0) *flag = (cnt > 16) ? 1 : 0;
}

struct ConvDesc { const void* src; float* dst; int n; };
struct ConvArgs { ConvDesc d[30]; };
__global__ void k_conv32(ConvArgs a, const int* __restrict__ flag) {
  ConvDesc de = a.d[blockIdx.y];
  int fp = *flag;
  for (int i = blockIdx.x*256 + threadIdx.x; i < de.n; i += gridDim.x*256)
    de.dst[i] = fp ? ((const float*)de.src)[i] : bf2f(((const u16*)de.src)[i]);
}

struct PackDesc { const float* src; u16* dh; u16* dl; int K, N, sk, sh; };
struct PackArgs { PackDesc d[32]; int n; };
__global__ void k_pack2(PackArgs a) {
  PackDesc de = a.d[blockIdx.y];
  int total = de.K * de.N;
  for (int i = blockIdx.x*256 + threadIdx.x; i < total; i += gridDim.x*256) {
    int k = i / de.N, n = i - k*de.N;
    float x = de.src[(size_t)k*de.sk + (n & 127) + (n >> 7)*de.sh];
    u16 h = f2bf(x);
    de.dh[(size_t)n*de.K + k] = h;
    de.dl[(size_t)n*de.K + k] = f2bf(x - bf2f(h));
  }
}

__global__ void k_init_nodes(const int* __restrict__ seq, const float* __restrict__ emb,
                             float* __restrict__ nodes_f, u16* __restrict__ nh) {
  int i = blockIdx.x*256 + threadIdx.x;
  if (i >= NN*DD) return;
  int n = i >> 7, d = i & 127;
  float v = emb[seq[n]*DD + d];
  nodes_f[i] = v;
  u16 h = f2bf(v); nh[i] = h; nh[NODE_LO + i] = f2bf(v - bf2f(h));
}

__global__ void k_rbf_s(const float* __restrict__ dist, const float* __restrict__ W,
                        const float* __restrict__ b, u16* __restrict__ eh) {
  int e = blockIdx.x, t = threadIdx.x;   // 128 threads/edge
  float d = dist[e];
  float acc = b[t];
#pragma unroll
  for (int k = 0; k < 16; ++k) {
    float mu = 2.f + (20.f/15.f)*(float)k;
    float z = (d - mu)*0.8f;
    float r = expf(-z*z) + 1e-8f;
    acc += r*W[k*DD + t];
  }
  size_t idx = (size_t)e*DD + t;
  u16 h = f2bf(acc); eh[idx] = h; eh[(size_t)EDGE_LO + idx] = f2bf(acc - bf2f(h));
}

__global__ void k_hist(const int* __restrict__ snk, int* __restrict__ deg) {
  int e = blockIdx.x*256 + threadIdx.x;
  if (e < EE) atomicAdd(&deg[snk[e]], 1);
}
__global__ void k_scan(const int* __restrict__ deg, int* __restrict__ ptr, int* __restrict__ cursor, int n) {
  __shared__ int buf[1024];
  __shared__ int carry_s;
  int tid = threadIdx.x;
  if (tid == 0) carry_s = 0;
  __syncthreads();
  for (int base = 0; base < n; base += 1024) {
    int i = base + tid;
    int v = (i < n) ? deg[i] : 0;
    buf[tid] = v;
    __syncthreads();
    for (int off = 1; off < 1024; off <<= 1) {
      int t = (tid >= off) ? buf[tid - off] : 0;
      __syncthreads();
      buf[tid] += t;
      __syncthreads();
    }
    int excl = buf[tid] - v;
    int carry = carry_s;
    if (i < n) { ptr[i] = carry + excl; cursor[i] = carry + excl; }
    __syncthreads();
    if (tid == 1023) carry_s = carry + buf[1023];
    __syncthreads();
  }
  if (tid == 0) ptr[n] = carry_s;
}
__global__ void k_scatter(const int* __restrict__ snk, int* __restrict__ cursor, int* __restrict__ csr) {
  int e = blockIdx.x*256 + threadIdx.x;
  if (e < EE) { int p = atomicAdd(&cursor[snk[e]], 1); csr[p] = e; }
}

// ---- fused scatter-softmax + aggregation: one block per node, 128 threads.
// Same math/order as before; nupd read from single bf16 plane.
__global__ void k_softmax_agg(const float* __restrict__ scores,
                              const int* __restrict__ ptr, const int* __restrict__ csr,
                              const u16* __restrict__ Xh,
                              u16* __restrict__ agg_h, u16* __restrict__ agg_l) {
  __shared__ float att_s[MAXDEG*4];
  __shared__ int   ce_s[MAXDEG];
  const int node = blockIdx.x, tid = threadIdx.x;
  const int b = ptr[node], e = ptr[node+1];
  int deg = e - b; if (deg > MAXDEG) deg = MAXDEG;   // Poisson(20): P(deg>256) ~ 0
  for (int i = tid; i < deg; i += 128) ce_s[i] = csr[b + i];
  __syncthreads();
  if (tid < 64) {
    int h = tid >> 4, j = tid & 15;
    float mx = -1e30f;
    for (int i = j; i < deg; i += 16) mx = fmaxf(mx, scores[(size_t)ce_s[i]*4 + h]);
    mx = fmaxf(mx, __shfl_xor(mx, 1, 64)); mx = fmaxf(mx, __shfl_xor(mx, 2, 64));
    mx = fmaxf(mx, __shfl_xor(mx, 4, 64)); mx = fmaxf(mx, __shfl_xor(mx, 8, 64));
    float s = 0.f;
    for (int i = j; i < deg; i += 16) s += expf(scores[(size_t)ce_s[i]*4 + h] - mx);
    s += __shfl_xor(s, 1, 64); s += __shfl_xor(s, 2, 64);
    s += __shfl_xor(s, 4, 64); s += __shfl_xor(s, 8, 64);
    float norm = s + (float)(e - b)*1e-12f;
    float inv = (e > b) ? 1.f/norm : 0.f;
    for (int i = j; i < deg; i += 16)
      att_s[i*4 + h] = expf(scores[(size_t)ce_s[i]*4 + h] - mx)*inv;
  }
  __syncthreads();
  const int d = tid;
  float a0=0.f, a1=0.f, a2=0.f, a3=0.f;
  for (int i = 0; i < deg; ++i) {
    int ed = ce_s[i];
    float4 a = *(const float4*)(att_s + i*4);
    float v = bf2f(Xh[(size_t)ed*DD + d]);
    a0 += a.x*v; a1 += a.y*v; a2 += a.z*v; a3 += a.w*v;
  }
  size_t o = (size_t)node*HDIM + d;
  float vv[4] = {a0, a1, a2, a3};
#pragma unroll
  for (int h = 0; h < 4; ++h) {
    u16 hi = f2bf(vv[h]);
    agg_h[o + h*128] = hi;
    agg_l[o + h*128] = f2bf(vv[h] - bf2f(hi));
  }
}

// mode 0: x = nodes_f + upd ; mode 1: x = dense_f + upd. Writes nodes_f + hi/lo planes.
__global__ void k_ln_node(float* __restrict__ nodes_f,
                          const float* __restrict__ upd, const float* __restrict__ dense_f,
                          const float* __restrict__ g, const float* __restrict__ b,
                          int mode, int rows, u16* __restrict__ nh) {
  int r = blockIdx.x*4 + (threadIdx.x >> 6);
  if (r >= rows) return;
  int lane = threadIdx.x & 63;
  size_t o = (size_t)r*DD;
  float x0, x1;
  if (mode == 0) { x0 = nodes_f[o+lane]; x1 = nodes_f[o+lane+64]; }
  else           { x0 = dense_f[o+lane]; x1 = dense_f[o+lane+64]; }
  x0 += upd[o+lane]; x1 += upd[o+lane+64];
  float s = x0 + x1;
#pragma unroll
  for (int m = 1; m < 64; m <<= 1) s += __shfl_xor(s, m, 64);
  float mean = s * (1.f/128.f);
  float d0 = x0 - mean, d1 = x1 - mean;
  float vv = d0*d0 + d1*d1;
#pragma unroll
  for (int m = 1; m < 64; m <<= 1) vv += __shfl_xor(vv, m, 64);
  float inv = rsqrtf(vv*(1.f/128.f) + 1e-5f);
  float v0 = d0*inv*g[lane]    + b[lane];
  float v1 = d1*inv*g[lane+64] + b[lane+64];
  nodes_f[o+lane]    = v0;
  nodes_f[o+lane+64] = v1;
  u16 h0 = f2bf(v0), h1 = f2bf(v1);
  nh[o+lane] = h0;    nh[NODE_LO + o+lane]    = f2bf(v0 - bf2f(h0));
  nh[o+lane+64] = h1; nh[NODE_LO + o+lane+64] = f2bf(v1 - bf2f(h1));
}

// residual read from eh hi/lo planes; eu from single bf16 X plane; writes back eh hi/lo
__global__ void k_ln_edge(const u16* __restrict__ Xh,
                          const float* __restrict__ g, const float* __restrict__ b,
                          int rows, u16* __restrict__ eh) {
  int r = blockIdx.x*4 + (threadIdx.x >> 6);
  if (r >= rows) return;
  int lane = threadIdx.x & 63;
  size_t o = (size_t)r*DD;
  float x0 = bf2f(eh[o+lane])    + bf2f(eh[(size_t)EDGE_LO + o+lane])    + bf2f(Xh[o+lane]);
  float x1 = bf2f(eh[o+lane+64]) + bf2f(eh[(size_t)EDGE_LO + o+lane+64]) + bf2f(Xh[o+lane+64]);
  float s = x0 + x1;
#pragma unroll
  for (int m = 1; m < 64; m <<= 1) s += __shfl_xor(s, m, 64);
  float mean = s * (1.f/128.f);
  float d0 = x0 - mean, d1 = x1 - mean;
  float vv = d0*d0 + d1*d1;
#pragma unroll
  for (int m = 1; m < 64; m <<= 1) vv += __shfl_xor(vv, m, 64);
  float inv = rsqrtf(vv*(1.f/128.f) + 1e-5f);
  float v0 = d0*inv*g[lane]    + b[lane];
  float v1 = d1*inv*g[lane+64] + b[lane+64];
  u16 h0 = f2bf(v0), h1 = f2bf(v1);
  eh[o+lane] = h0;    eh[(size_t)EDGE_LO + o+lane]    = f2bf(v0 - bf2f(h0));
  eh[o+lane+64] = h1; eh[(size_t)EDGE_LO + o+lane+64] = f2bf(v1 - bf2f(h1));
}

__global__ void k_finalize(const float* __restrict__ nodes_f, const u16* __restrict__ eh,
                           void* __restrict__ out, const int* __restrict__ flag) {
  int i = blockIdx.x*256 + threadIdx.x;
  if (i >= OUT_TOTAL) return;
  int fp = *flag;
  float v;
  if (i < OUT_NODES) v = nodes_f[i];
  else { int j = i - OUT_NODES; v = bf2f(eh[j]) + bf2f(eh[(size_t)EDGE_LO + j]); }
  if (fp) ((float*)out)[i] = v; else ((u16*)out)[i] = f2bf(v);
}

extern "C" void kernel_launch(void* const* d_in, const int* in_sizes, int n_in,
                              void* d_out, int out_size, void* d_ws, size_t ws_size,
                              hipStream_t stream)
{
  const int* seq_idx = (const int*)d_in[0];
  const int* esrc = (const int*)d_in[1];
  const int* esnk = ((const int*)d_in[1]) + EE;

  char* wsp = (char*)d_ws;
  size_t off = 0;
  auto carve = [&](size_t bytes)->char* {
    char* p = wsp + off; off += (bytes + 255) & ~(size_t)255; return p;
  };
  // Total ~187 MB (layout matches R12 exactly; X_l half now dead)
  int* flag       = (int*)carve(256);
  float* nodes_f  = (float*)carve((size_t)NN*DD*4);
  float* upd_f    = (float*)carve((size_t)NN*DD*4);
  float* scores   = (float*)carve((size_t)EE*4*4);
  float* pad_att  = (float*)carve((size_t)EE*4*4);   // dead: keeps R12 buffer addresses
  float* dense_f  = (float*)carve((size_t)NN*DD*4);
  u16* Zatt       = (u16*)carve((size_t)NN*1024*2);     // bf16 node projections for scores
  u16* wpk_h      = (u16*)carve(557056ULL*2*2);
  u16* wpk_l      = (u16*)carve(557056ULL*2*2);
  int* deg        = (int*)carve((size_t)NN*4);
  int* ptrb       = (int*)carve((size_t)(NN+1)*4);
  int* cursor     = (int*)carve((size_t)NN*4);
  int* csr        = (int*)carve((size_t)EE*4);
  u16* nodes_h    = (u16*)carve((size_t)2*NN*DD*2);     // [hi | lo]
  u16* eattr_h    = (u16*)carve((size_t)2*EE*DD*2);     // [hi | lo]
  u16* X_h        = (u16*)carve((size_t)2*EE*DD*2);     // activation (bf16; lo half dead)
  u16* agg_h      = (u16*)carve((size_t)2*NN*HDIM*2);
  u16* dh_h       = (u16*)carve((size_t)2*NN*HDIM*2);
  u16* agg_l = agg_h + (size_t)NN*HDIM;
  u16* dh_l  = dh_h  + (size_t)NN*HDIM;
  (void)pad_att;

  static const int FCNT[32] = {0,0,120000,2688,2048,128,393216,1024,1024,8,
    98304,256,32768,256,32768,256, 131072,1024,131072,256,
    98304,256,32768,256,32768,256, 131072,256, 256,256,256,256};
  float* cf[32];
  for (int i = 2; i < 32; ++i) cf[i] = (float*)carve((size_t)FCNT[i]*4);
  (void)ws_size; (void)in_sizes; (void)n_in; (void)out_size;

  // ---- detect float storage dtype, canonicalize to FP32 arena ----
  k_detect<<<1, 1024, 0, stream>>>((const u16*)d_in[2], 120000, flag);
  ConvArgs ca;
  for (int i = 2; i < 32; ++i) { ca.d[i-2].src = d_in[i]; ca.d[i-2].dst = cf[i]; ca.d[i-2].n = FCNT[i]; }
  hipLaunchKernelGGL(k_conv32, dim3(96, 30), dim3(256), 0, stream, ca, flag);

  // ---- pack weights to [N,K] split hi/lo bf16 ----
  const size_t PW_L = 557056;
  PackArgs pa; int nd = 0;
  for (int l = 0; l < 2; ++l) {
    size_t base = l*PW_L;
    auto add = [&](const float* s, size_t doff, int K, int N, int sk, int sh){
      pa.d[nd].src = s; pa.d[nd].dh = wpk_h + doff; pa.d[nd].dl = wpk_l + doff;
      pa.d[nd].K = K; pa.d[nd].N = N; pa.d[nd].sk = sk; pa.d[nd].sh = sh; ++nd; };
    const float* aW = cf[6] + l*196608;
    add(aW,          base + 0,      128, 512, 128, 49152);  // aW src-slice
    add(aW + 16384,  base + 65536,  128, 512, 128, 49152);  // aW snk-slice
    add(aW + 32768,  base + 131072, 128, 512, 128, 49152);  // aW edge-slice
    add(cf[10] + l*49152, base + 196608, 384, 128, 128, 0); // nmlp_W1 (full K=384)
    add(cf[12] + l*16384, base + 245760, 128, 128, 128, 0); // nmlp_W2
    add(cf[14] + l*16384, base + 262144, 128, 128, 128, 0); // nmlp_W3
    add(cf[26] + l*65536, base + 278528, 512, 128, 128, 0); // aggr_W
    add(cf[16] + l*65536, base + 344064, 128, 512, 512, 128); // dmlp_W1
    add(cf[18] + l*65536, base + 409600, 512, 128, 128, 0); // dmlp_W2
    add(cf[20] + l*49152, base + 475136, 384, 128, 128, 0); // emlp_W1 (full K=384)
    add(cf[22] + l*16384, base + 524288, 128, 128, 128, 0); // emlp_W2
    add(cf[24] + l*16384, base + 540672, 128, 128, 128, 0); // emlp_W3
  }
  pa.n = nd;
  hipLaunchKernelGGL(k_pack2, dim3(256, nd), dim3(256), 0, stream, pa);

  k_init_nodes<<<(NN*DD + 255)/256, 256, 0, stream>>>(seq_idx, cf[3], nodes_f, nodes_h);
  k_rbf_s<<<EE, 128, 0, stream>>>(cf[2], cf[4], cf[5], eattr_h);

  (void)hipMemsetAsync(deg, 0, (size_t)NN*4, stream);
  k_hist<<<(EE + 255)/256, 256, 0, stream>>>(esnk, deg);
  k_scan<<<1, 1024, 0, stream>>>(deg, ptrb, cursor, NN);
  k_scatter<<<(EE + 255)/256, 256, 0, stream>>>(esnk, cursor, csr);

  for (int l = 0; l < 2; ++l) {
    const u16* bh = wpk_h + l*PW_L; const u16* bl = wpk_l + l*PW_L;
    // node projections for scores: Zatt[n][1024] (bf16) = nodes @ [aW_src|aW_snk]
    k_gemm2<<<dim3(47, 8), 256, 0, stream>>>(nodes_h, nodes_h + NODE_LO, 128,
        bh + 0, bl + 0, nullptr, nullptr, Zatt, nullptr, NN, 1024, 8);
    // attention scores: K=128 edge GEMM (csr order, eattr-hi only) + bf16 Z gather + aA reduce
    k_score<<<dim3(3752), 256, 0, stream>>>(eattr_h, esrc, esnk, csr,
        bh + 131072, bl + 131072, cf[7] + l*512, cf[8] + l*512, cf[9] + l*4,
        Zatt, scores, EE);
    // node-update MLP chain: W1(gelu)->W2(gelu)->W3 -> X (single bf16 plane)
    k_mlp_chain<<<dim3(938), 256, 0, stream>>>(nodes_h, eattr_h, esrc, esnk,
        bh + 196608, bl + 196608, cf[11] + l*128,
        bh + 245760, bl + 245760, cf[13] + l*128,
        bh + 262144, bl + 262144, cf[15] + l*128,
        X_h, EE);
    // fused scatter-softmax + aggregation (reads nupd bf16 from X)
    k_softmax_agg<<<NN, 128, 0, stream>>>(scores, ptrb, csr, X_h, agg_h, agg_l);
    // upd = agg @ aggr_W + b  (fp32 out)
    k_gemm2<<<dim3(47, 1), 256, 0, stream>>>(agg_h, agg_l, 512, bh + 278528, bl + 278528,
        cf[27] + l*128, upd_f, nullptr, nullptr, NN, 128, 3);
    k_ln_node<<<(NN + 3)/4, 256, 0, stream>>>(nodes_f, upd_f, (const float*)nullptr,
        cf[28] + l*128, cf[29] + l*128, 0, NN, nodes_h);
    // dense MLP
    k_gemm2<<<dim3(47, 4), 256, 0, stream>>>(nodes_h, nodes_h + NODE_LO, 128,
        bh + 344064, bl + 344064, cf[17] + l*512, nullptr, dh_h, dh_l, NN, 512, 5);
    k_gemm2<<<dim3(47, 1), 256, 0, stream>>>(dh_h, dh_l, 512, bh + 409600, bl + 409600,
        cf[19] + l*128, dense_f, nullptr, nullptr, NN, 128, 3);
    k_ln_node<<<(NN + 3)/4, 256, 0, stream>>>(nodes_f, upd_f, dense_f,
        cf[28] + l*128, cf[29] + l*128, 1, NN, nodes_h);
    // edge MLP chain: W1(gelu)->W2(gelu)->W3 -> X (bf16), then separate LN
    k_mlp_chain<<<dim3(938), 256, 0, stream>>>(nodes_h, eattr_h, esrc, esnk,
        bh + 475136, bl + 475136, cf[21] + l*128,
        bh + 524288, bl + 524288, cf[23] + l*128,
        bh + 540672, bl + 540672, cf[25] + l*128,
        X_h, EE);
    k_ln_edge<<<(EE + 3)/4, 256, 0, stream>>>(X_h,
        cf[30] + l*128, cf[31] + l*128, EE, eattr_h);
  }
  k_finalize<<<(OUT_TOTAL + 255)/256, 256, 0, stream>>>(nodes_f, eattr_h, d_out, flag);
}